// Round 10
// baseline (75.862 us; speedup 1.0000x reference)
//
#include <hip/hip_runtime.h>
#include <stdint.h>

#define SEQ 4096
#define FDIM 128
#define NH 4
#define HD 32
#define NB 2
#define NROWS (NB * NH * SEQ)  // 32768
#define LOG2E 1.4426950408889634f
#define VCOL 68            // shorts per Vp column (34 dwords)
#define VHALF (32 * VCOL)  // shorts per Vp buffer (4352 B)

typedef float f32x4 __attribute__((ext_vector_type(4)));
typedef __bf16 bf16x8 __attribute__((ext_vector_type(8)));

__device__ __forceinline__ unsigned short f2bf(float f) {
  unsigned int u = __builtin_bit_cast(unsigned int, f);
  return (unsigned short)((u + 0x7FFFu + ((u >> 16) & 1u)) >> 16);  // RTNE
}

// ---- pre-pass 1: fp32 -> bf16 ----
__global__ void cvt_kernel(const float* __restrict__ in, unsigned short* __restrict__ out) {
  int i = (blockIdx.x * 256 + threadIdx.x) * 4;
  float4 v = *reinterpret_cast<const float4*>(in + i);
  ushort4 o;
  o.x = f2bf(v.x); o.y = f2bf(v.y); o.z = f2bf(v.z); o.w = f2bf(v.w);
  *reinterpret_cast<ushort4*>(out + i) = o;
}

// ---- pre-pass 2: adjacency int32 -> bitmask; 16 ints/thread ----
__global__ void adjpack_kernel(const int* __restrict__ adj, unsigned short* __restrict__ bits16) {
  size_t t = (size_t)blockIdx.x * 256 + threadIdx.x;
  const uint4* p = reinterpret_cast<const uint4*>(adj) + t * 4;
  uint4 a = p[0], b = p[1], c = p[2], d = p[3];
  unsigned m = 0;
  m |= (a.x != 0) ? 1u : 0u;        m |= (a.y != 0) ? 2u : 0u;
  m |= (a.z != 0) ? 4u : 0u;        m |= (a.w != 0) ? 8u : 0u;
  m |= (b.x != 0) ? 16u : 0u;       m |= (b.y != 0) ? 32u : 0u;
  m |= (b.z != 0) ? 64u : 0u;       m |= (b.w != 0) ? 128u : 0u;
  m |= (c.x != 0) ? 256u : 0u;      m |= (c.y != 0) ? 512u : 0u;
  m |= (c.z != 0) ? 1024u : 0u;     m |= (c.w != 0) ? 2048u : 0u;
  m |= (d.x != 0) ? 4096u : 0u;     m |= (d.y != 0) ? 8192u : 0u;
  m |= (d.z != 0) ? 16384u : 0u;    m |= (d.w != 0) ? 32768u : 0u;
  bits16[t] = (unsigned short)m;
}

// One tile step, single barrier. RB = read buffer, WBUF = write buffer.
// K staged by DMA (global_load_lds, linear layout, zero VALU); V staged via
// registers + perm transpose. Compiler drains vmcnt before each s_barrier.
#define STEP(T, RB, WBUF)                                                       \
  {                                                                             \
    __syncthreads();                                                            \
    const bool pfok = (T) + 1 < NT;                                             \
    if (pfok) { /* issue tile T+1 staging: K DMA + V reg loads */               \
      kgp += 64 * FDIM;                                                         \
      __builtin_amdgcn_global_load_lds(                                         \
          (__attribute__((address_space(1))) const unsigned int*)kgp,           \
          (__attribute__((address_space(3))) unsigned int*)(&Klin[WBUF][wid * 512]), \
          16, 0, 0);                                                            \
      sptr += 64 * FDIM;                                                        \
      r0 = *reinterpret_cast<const uint2*>(sptr);                               \
      r1 = *reinterpret_cast<const uint2*>(sptr + FDIM);                        \
      wnext = brow[bcol0 + (T) + 1];                                            \
    }                                                                           \
    f32x4 sc[4];                                                                \
    __builtin_amdgcn_s_setprio(1);                                              \
    _Pragma("unroll") for (int t4 = 0; t4 < 4; ++t4) {                          \
      bf16x8 kf = __builtin_bit_cast(bf16x8,                                    \
          *reinterpret_cast<const uint4*>(&Klin[RB][t4 * 512 + ql * 32 + g * 8])); \
      sc[t4] = __builtin_amdgcn_mfma_f32_16x16x32_bf16(kf, qf, zf, 0, 0, 0);    \
    }                                                                           \
    __builtin_amdgcn_s_setprio(0);                                              \
    const unsigned long long wsh = wcur >> (4 * g);                             \
    const int mwl = (int)(unsigned)wsh, mwh = (int)(unsigned)(wsh >> 32);       \
    float pf4[4][4];                                                            \
    _Pragma("unroll") for (int t4 = 0; t4 < 4; ++t4) {                          \
      const int word = (t4 & 2) ? mwh : mwl;                                    \
      _Pragma("unroll") for (int r = 0; r < 4; ++r) {                           \
        float v = sc[t4][r];                                                    \
        v = fmaxf(v, 0.2f * v);                       /* leaky_relu */          \
        float e = __builtin_amdgcn_exp2f(v);          /* unshifted exp2 */      \
        const int msk = __builtin_amdgcn_sbfe(word, 16 * (t4 & 1) + r, 1);      \
        pf4[t4][r] = __builtin_bit_cast(                                        \
            float, __builtin_bit_cast(unsigned, e) & (unsigned)msk);            \
      }                                                                         \
    }                                                                           \
    __builtin_amdgcn_s_setprio(1);                                              \
    _Pragma("unroll") for (int u = 0; u < 2; ++u) {                             \
      bf16x8 pa;                                                                \
      _Pragma("unroll") for (int tp = 0; tp < 2; ++tp)                          \
          _Pragma("unroll") for (int r = 0; r < 4; ++r)                         \
              pa[tp * 4 + r] = (__bf16)pf4[2 * u + tp][r];                      \
      bf16x8 vf0 = __builtin_bit_cast(bf16x8,                                   \
          *reinterpret_cast<const uint4*>(&Vp[RB][ql * VCOL + u * 32 + g * 8]));        \
      bf16x8 vf1 = __builtin_bit_cast(bf16x8,                                   \
          *reinterpret_cast<const uint4*>(&Vp[RB][(16 + ql) * VCOL + u * 32 + g * 8])); \
      acc0 = __builtin_amdgcn_mfma_f32_16x16x32_bf16(pa, vf0, acc0, 0, 0, 0);   \
      acc1 = __builtin_amdgcn_mfma_f32_16x16x32_bf16(pa, vf1, acc1, 0, 0, 0);   \
      accL = __builtin_amdgcn_mfma_f32_16x16x32_bf16(pa, ones, accL, 0, 0, 0);  \
    }                                                                           \
    __builtin_amdgcn_s_setprio(0);                                              \
    if (pfok) { /* V transpose-write into the other buffer */                   \
      unsigned* vw = reinterpret_cast<unsigned*>(&Vp[WBUF][0]) + pi0h;          \
      vw[(4 * c4 + 0) * 34] = __builtin_amdgcn_perm(r1.x, r0.x, selA);          \
      vw[(4 * c4 + 1) * 34] = __builtin_amdgcn_perm(r1.x, r0.x, selB);          \
      vw[(4 * c4 + 2) * 34] = __builtin_amdgcn_perm(r1.y, r0.y, selA);          \
      vw[(4 * c4 + 3) * 34] = __builtin_amdgcn_perm(r1.y, r0.y, selB);          \
    }                                                                           \
    wcur = wnext;                                                               \
  }

// ---- main fused attention kernel ----
// Grid: (SEQ/64, NB*NH, NSPLIT). 4 waves/block, each wave owns 16 q-rows.
// K: linear LDS [64][32] via global_load_lds DMA (conflict-free b128 reads,
// banks perfectly balanced by construction). V: pi-col-major, perm-transposed.
// Both double-buffered; one barrier per tile. Static-max softmax; l via
// ones-MFMA; sbfe-AND mask.
template <int NSPLIT>
__global__ __launch_bounds__(256, 4) void gat_kernel(
    const unsigned short* __restrict__ xbf,
    const unsigned long long* __restrict__ bits,
    float* __restrict__ dst,     // NSPLIT==1: final out ; else: Opart
    float* __restrict__ lbuf) {  // NSPLIT>1 only: [split][row] = l
  __shared__ __align__(16) unsigned short Klin[2][64 * 32];  // 2 x 4096 B
  __shared__ __align__(16) unsigned short Vp[2][VHALF];      // 2 x 4352 B

  const int bh = blockIdx.y;
  const int b = bh >> 2;
  const int h = bh & 3;
  const int tid = threadIdx.x;
  const int wid = tid >> 6;
  const int lane = tid & 63;
  const int g = lane >> 4;
  const int ql = lane & 15;
  const int qw = blockIdx.x * 64 + wid * 16;
  const int jbase = blockIdx.z * (SEQ / NSPLIT);
  const int NT = (SEQ / NSPLIT) / 64;

  const unsigned short* xb = xbf + ((size_t)b * SEQ) * FDIM + h * HD;

  // Q fragment, pre-scaled by log2(e) so exp(x) == exp2(score)
  bf16x8 qraw = __builtin_bit_cast(bf16x8,
      *reinterpret_cast<const uint4*>(xb + (size_t)(qw + ql) * FDIM + g * 8));
  bf16x8 qf;
#pragma unroll
  for (int e = 0; e < 8; ++e) qf[e] = (__bf16)((float)qraw[e] * LOG2E);

  bf16x8 ones;
#pragma unroll
  for (int e = 0; e < 8; ++e) ones[e] = (__bf16)1.0f;
  const f32x4 zf = {0.f, 0.f, 0.f, 0.f};

  f32x4 acc0 = {0.f, 0.f, 0.f, 0.f};  // O[row=4g+r][col=ql]
  f32x4 acc1 = {0.f, 0.f, 0.f, 0.f};  // O[row=4g+r][col=16+ql]
  f32x4 accL = {0.f, 0.f, 0.f, 0.f};  // l[row=4g+r]

  const unsigned long long* brow = bits + (size_t)(qw + ql) * (SEQ / 64);
  const int bcol0 = jbase >> 6;

  // K DMA map: wave w stages rows w*16..w*16+15; lane l -> row w*16+(l>>2),
  // 16B chunk (l&3). LDS dest = Klin[buf] + w*512 shorts (+ lane*16B by HW).
  const unsigned short* kgp =
      xb + (size_t)(jbase + wid * 16 + (lane >> 2)) * FDIM + (lane & 3) * 8;

  // V staging map: rows (2*pr, 2*pr+1), cols 4*c4..4*c4+3; pr bit-remapped so
  // each wave's pi0h covers all 8 residues mod 8 (write banks spread).
  const int s3 = (tid >> 3) & 7;
  const int pr = (s3 & 1) | (((s3 >> 1) & 1) << 1) | ((wid & 1) << 2) |
                 (((s3 >> 2) & 1) << 3) | ((wid >> 1) << 4);
  const int c4 = tid & 7;
  const unsigned short* sptr = xb + (size_t)(jbase + 2 * pr) * FDIM + c4 * 4;

  // pi(j): j=[u|tp|g|r] (bits 5|4|3:2|1:0) -> [u|g|tp|r]; pi0h = pi(2pr)/2
  const int pi0h = 16 * (pr >> 4) + 4 * ((pr >> 1) & 3) + 2 * ((pr >> 3) & 1) + (pr & 1);

  const unsigned selA = 0x05040100u;  // [lo.b0, lo.b1, hi.b0, hi.b1]
  const unsigned selB = 0x07060302u;  // [lo.b2, lo.b3, hi.b2, hi.b3]

  // prologue: stage tile 0 into buffer 0 (K DMA + V transpose)
  __builtin_amdgcn_global_load_lds(
      (__attribute__((address_space(1))) const unsigned int*)kgp,
      (__attribute__((address_space(3))) unsigned int*)(&Klin[0][wid * 512]),
      16, 0, 0);
  uint2 r0 = *reinterpret_cast<const uint2*>(sptr);
  uint2 r1 = *reinterpret_cast<const uint2*>(sptr + FDIM);
  unsigned long long wcur = brow[bcol0];
  unsigned long long wnext = 0;
  {
    unsigned* vw = reinterpret_cast<unsigned*>(&Vp[0][0]) + pi0h;
    vw[(4 * c4 + 0) * 34] = __builtin_amdgcn_perm(r1.x, r0.x, selA);
    vw[(4 * c4 + 1) * 34] = __builtin_amdgcn_perm(r1.x, r0.x, selB);
    vw[(4 * c4 + 2) * 34] = __builtin_amdgcn_perm(r1.y, r0.y, selA);
    vw[(4 * c4 + 3) * 34] = __builtin_amdgcn_perm(r1.y, r0.y, selB);
  }

  for (int t = 0; t < NT; t += 2) {
    STEP(t, 0, 1);
    STEP(t + 1, 1, 0);
  }

  if (NSPLIT == 1) {
#pragma unroll
    for (int r = 0; r < 4; ++r) {
      const float inv = 1.f / accL[r];
      const size_t o = ((size_t)b * SEQ + (size_t)(qw + 4 * g + r)) * FDIM + h * HD;
      dst[o + ql] = acc0[r] * inv;
      dst[o + 16 + ql] = acc1[r] * inv;
    }
  } else {
    float* Op = dst + (((size_t)blockIdx.z * (NB * NH) + bh) * SEQ) * HD;
#pragma unroll
    for (int r = 0; r < 4; ++r) {
      const int q = qw + 4 * g + r;
      Op[(size_t)q * HD + ql] = acc0[r];
      Op[(size_t)q * HD + 16 + ql] = acc1[r];
    }
    if (ql == 0) {
#pragma unroll
      for (int r = 0; r < 4; ++r)
        lbuf[(size_t)blockIdx.z * NROWS + (size_t)bh * SEQ + qw + 4 * g + r] = accL[r];
    }
  }
}

// ---- combine partials (split path): out = sum(O_s) / sum(l_s) ----
template <int NSPLIT>
__global__ __launch_bounds__(256) void combine_kernel(
    const float* __restrict__ Op, const float* __restrict__ lbuf, float* __restrict__ out) {
  const int idx = blockIdx.x * 256 + threadIdx.x;  // unit: 4 floats
  const int row = idx >> 3;
  const int dc = (idx & 7) * 4;
  float lt = 0.f;
  float4 o = {0.f, 0.f, 0.f, 0.f};
#pragma unroll
  for (int s = 0; s < NSPLIT; ++s) {
    lt += lbuf[(size_t)s * NROWS + row];
    float4 v = *reinterpret_cast<const float4*>(Op + ((size_t)s * NROWS + row) * HD + dc);
    o.x += v.x; o.y += v.y; o.z += v.z; o.w += v.w;
  }
  const float inv = 1.f / lt;
  const int bh = row >> 12;
  const int q = row & (SEQ - 1);
  const int b = bh >> 2;
  const int h = bh & 3;
  float4 w;
  w.x = o.x * inv; w.y = o.y * inv; w.z = o.z * inv; w.w = o.w * inv;
  *reinterpret_cast<float4*>(out + ((size_t)b * SEQ + q) * FDIM + h * HD + dc) = w;
}

extern "C" void kernel_launch(void* const* d_in, const int* in_sizes, int n_in,
                              void* d_out, int out_size, void* d_ws, size_t ws_size,
                              hipStream_t stream) {
  (void)in_sizes; (void)n_in; (void)out_size;
  const float* x = (const float*)d_in[0];
  const int* adj = (const int*)d_in[1];
  float* outp = (float*)d_out;

  unsigned short* xbf = (unsigned short*)d_ws;                           // 2 MiB
  unsigned short* bits16 = (unsigned short*)((char*)d_ws + (2u << 20));  // 2 MiB
  float* Opart = (float*)((char*)d_ws + (4u << 20));
  auto need = [](int s) {
    return (size_t)(4u << 20) + (size_t)s * NROWS * HD * 4 + (size_t)s * NROWS * 4;
  };

  cvt_kernel<<<(NB * SEQ * FDIM) / (256 * 4), 256, 0, stream>>>(x, xbf);
  adjpack_kernel<<<(SEQ * SEQ) / (16 * 256), 256, 0, stream>>>(adj, bits16);

  const unsigned long long* bits = (const unsigned long long*)bits16;
  if (ws_size >= need(4)) {
    float* mlb = (float*)((char*)d_ws + (4u << 20) + (size_t)4 * NROWS * HD * 4);
    dim3 grid(SEQ / 64, NB * NH, 4);
    gat_kernel<4><<<grid, 256, 0, stream>>>(xbf, bits, Opart, mlb);
    combine_kernel<4><<<(NROWS * 8) / 256, 256, 0, stream>>>(Opart, mlb, outp);
  } else if (ws_size >= need(2)) {
    float* mlb = (float*)((char*)d_ws + (4u << 20) + (size_t)2 * NROWS * HD * 4);
    dim3 grid(SEQ / 64, NB * NH, 2);
    gat_kernel<2><<<grid, 256, 0, stream>>>(xbf, bits, Opart, mlb);
    combine_kernel<2><<<(NROWS * 8) / 256, 256, 0, stream>>>(Opart, mlb, outp);
  } else {
    dim3 grid(SEQ / 64, NB * NH, 1);
    gat_kernel<1><<<grid, 256, 0, stream>>>(xbf, bits, outp, nullptr);
  }
}

// Round 11
// 73.175 us; speedup vs baseline: 1.0367x; 1.0367x over previous
//
#include <hip/hip_runtime.h>
#include <stdint.h>

#define SEQ 4096
#define FDIM 128
#define NH 4
#define HD 32
#define NB 2
#define NROWS (NB * NH * SEQ)  // 32768
#define LOG2E 1.4426950408889634f
#define KVB 128            // j-tile size
#define VCS 136            // shorts per Vp column (68 dwords: 128 data + 8 pad)
#define VPHALF (32 * VCS)  // shorts per Vp buffer (8704 B)

typedef float f32x4 __attribute__((ext_vector_type(4)));
typedef __bf16 bf16x8 __attribute__((ext_vector_type(8)));

__device__ __forceinline__ unsigned short f2bf(float f) {
  unsigned int u = __builtin_bit_cast(unsigned int, f);
  return (unsigned short)((u + 0x7FFFu + ((u >> 16) & 1u)) >> 16);  // RTNE
}

// ---- pre-pass 1: fp32 -> bf16 ----
__global__ void cvt_kernel(const float* __restrict__ in, unsigned short* __restrict__ out) {
  int i = (blockIdx.x * 256 + threadIdx.x) * 4;
  float4 v = *reinterpret_cast<const float4*>(in + i);
  ushort4 o;
  o.x = f2bf(v.x); o.y = f2bf(v.y); o.z = f2bf(v.z); o.w = f2bf(v.w);
  *reinterpret_cast<ushort4*>(out + i) = o;
}

// ---- pre-pass 2: adjacency int32 -> bitmask; 16 ints/thread ----
__global__ void adjpack_kernel(const int* __restrict__ adj, unsigned short* __restrict__ bits16) {
  size_t t = (size_t)blockIdx.x * 256 + threadIdx.x;
  const uint4* p = reinterpret_cast<const uint4*>(adj) + t * 4;
  uint4 a = p[0], b = p[1], c = p[2], d = p[3];
  unsigned m = 0;
  m |= (a.x != 0) ? 1u : 0u;        m |= (a.y != 0) ? 2u : 0u;
  m |= (a.z != 0) ? 4u : 0u;        m |= (a.w != 0) ? 8u : 0u;
  m |= (b.x != 0) ? 16u : 0u;       m |= (b.y != 0) ? 32u : 0u;
  m |= (b.z != 0) ? 64u : 0u;       m |= (b.w != 0) ? 128u : 0u;
  m |= (c.x != 0) ? 256u : 0u;      m |= (c.y != 0) ? 512u : 0u;
  m |= (c.z != 0) ? 1024u : 0u;     m |= (c.w != 0) ? 2048u : 0u;
  m |= (d.x != 0) ? 4096u : 0u;     m |= (d.y != 0) ? 8192u : 0u;
  m |= (d.z != 0) ? 16384u : 0u;    m |= (d.w != 0) ? 32768u : 0u;
  bits16[t] = (unsigned short)m;
}

// One 128-j tile step, single barrier. RB = read buffer, WBUF = write buffer.
#define STEP(T, RB, WBUF)                                                       \
  {                                                                             \
    __syncthreads();                                                            \
    const bool pfok = (T) + 1 < NT;                                             \
    if (pfok) { /* prefetch tile T+1 staging data (consumed at step end) */     \
      kptr += KVB * FDIM;                                                       \
      k0 = *reinterpret_cast<const uint4*>(kptr);                               \
      k1 = *reinterpret_cast<const uint4*>(kptr + 64 * FDIM);                   \
      sptr += KVB * FDIM;                                                       \
      r0 = *reinterpret_cast<const uint2*>(sptr);                               \
      r1 = *reinterpret_cast<const uint2*>(sptr + FDIM);                        \
      r2 = *reinterpret_cast<const uint2*>(sptr + 64 * FDIM);                   \
      r3 = *reinterpret_cast<const uint2*>(sptr + 65 * FDIM);                   \
      wnv = *reinterpret_cast<const uint4*>(&brow[bcol0 + 2 * ((T) + 1)]);      \
    }                                                                           \
    _Pragma("unroll") for (int hf = 0; hf < 2; ++hf) {                          \
      f32x4 sc[4];                                                              \
      __builtin_amdgcn_s_setprio(1);                                            \
      _Pragma("unroll") for (int t4 = 0; t4 < 4; ++t4) {                        \
        bf16x8 kf = __builtin_bit_cast(bf16x8,                                  \
            *reinterpret_cast<const uint4*>(                                    \
                &Kl[RB][hf * 64 + t4 * 16 + ql][g * 8]));                       \
        sc[t4] = __builtin_amdgcn_mfma_f32_16x16x32_bf16(kf, qf, zf, 0, 0, 0);  \
      }                                                                         \
      __builtin_amdgcn_s_setprio(0);                                            \
      const unsigned long long wsh = (hf ? wc1 : wc0) >> (4 * g);               \
      const int mwl = (int)(unsigned)wsh, mwh = (int)(unsigned)(wsh >> 32);     \
      float pf4[4][4];                                                          \
      _Pragma("unroll") for (int t4 = 0; t4 < 4; ++t4) {                        \
        const int word = (t4 & 2) ? mwh : mwl;                                  \
        _Pragma("unroll") for (int r = 0; r < 4; ++r) {                         \
          float v = sc[t4][r];                                                  \
          v = fmaxf(v, 0.2f * v);                       /* leaky_relu */        \
          float e = __builtin_amdgcn_exp2f(v);          /* unshifted exp2 */    \
          const int msk = __builtin_amdgcn_sbfe(word, 16 * (t4 & 1) + r, 1);    \
          pf4[t4][r] = __builtin_bit_cast(                                      \
              float, __builtin_bit_cast(unsigned, e) & (unsigned)msk);          \
        }                                                                       \
      }                                                                         \
      __builtin_amdgcn_s_setprio(1);                                            \
      _Pragma("unroll") for (int uu = 0; uu < 2; ++uu) {                        \
        const int u = 2 * hf + uu;                                              \
        bf16x8 pa;                                                              \
        _Pragma("unroll") for (int tp = 0; tp < 2; ++tp)                        \
            _Pragma("unroll") for (int r = 0; r < 4; ++r)                       \
                pa[tp * 4 + r] = (__bf16)pf4[2 * uu + tp][r];                   \
        bf16x8 vf0 = __builtin_bit_cast(bf16x8,                                 \
            *reinterpret_cast<const uint4*>(&Vp[RB][ql * VCS + u * 32 + g * 8]));        \
        bf16x8 vf1 = __builtin_bit_cast(bf16x8,                                 \
            *reinterpret_cast<const uint4*>(&Vp[RB][(16 + ql) * VCS + u * 32 + g * 8])); \
        acc0 = __builtin_amdgcn_mfma_f32_16x16x32_bf16(pa, vf0, acc0, 0, 0, 0); \
        acc1 = __builtin_amdgcn_mfma_f32_16x16x32_bf16(pa, vf1, acc1, 0, 0, 0); \
        accL = __builtin_amdgcn_mfma_f32_16x16x32_bf16(pa, ones, accL, 0, 0, 0);\
      }                                                                         \
      __builtin_amdgcn_s_setprio(0);                                            \
    }                                                                           \
    if (pfok) { /* stage tile T+1 into the other buffer (no barrier needed) */  \
      *reinterpret_cast<uint4*>(&Kl[WBUF][krow][kq * 8]) = k0;                  \
      *reinterpret_cast<uint4*>(&Kl[WBUF][64 + krow][kq * 8]) = k1;             \
      unsigned* vw = reinterpret_cast<unsigned*>(&Vp[WBUF][0]) + pi0h;          \
      vw[(4 * c4 + 0) * 68] = __builtin_amdgcn_perm(r1.x, r0.x, selA);          \
      vw[(4 * c4 + 1) * 68] = __builtin_amdgcn_perm(r1.x, r0.x, selB);          \
      vw[(4 * c4 + 2) * 68] = __builtin_amdgcn_perm(r1.y, r0.y, selA);          \
      vw[(4 * c4 + 3) * 68] = __builtin_amdgcn_perm(r1.y, r0.y, selB);          \
      vw[(4 * c4 + 0) * 68 + 32] = __builtin_amdgcn_perm(r3.x, r2.x, selA);     \
      vw[(4 * c4 + 1) * 68 + 32] = __builtin_amdgcn_perm(r3.x, r2.x, selB);     \
      vw[(4 * c4 + 2) * 68 + 32] = __builtin_amdgcn_perm(r3.y, r2.y, selA);     \
      vw[(4 * c4 + 3) * 68 + 32] = __builtin_amdgcn_perm(r3.y, r2.y, selB);     \
    }                                                                           \
    wc0 = (unsigned long long)wnv.x | ((unsigned long long)wnv.y << 32);        \
    wc1 = (unsigned long long)wnv.z | ((unsigned long long)wnv.w << 32);        \
  }

// ---- main fused attention kernel ----
// Grid: (SEQ/64, NB*NH, NSPLIT). 4 waves/block, each wave owns 16 q-rows.
// 128-j tiles: two half-tiles per barrier (8 QK + 8 PV + 4 L MFMAs), one 16B
// adjacency load per tile. K [128][40] + V pi-col-major (stride 68dw, halves
// at +32dw) double-buffered; conflict-free staging maps from R7.
template <int NSPLIT>
__global__ __launch_bounds__(256, 4) void gat_kernel(
    const unsigned short* __restrict__ xbf,
    const unsigned long long* __restrict__ bits,
    float* __restrict__ dst,     // NSPLIT==1: final out ; else: Opart
    float* __restrict__ lbuf) {  // NSPLIT>1 only: [split][row] = l
  __shared__ __align__(16) unsigned short Kl[2][KVB][40];  // 2 x 10240 B
  __shared__ __align__(16) unsigned short Vp[2][VPHALF];   // 2 x 8704 B

  const int bh = blockIdx.y;
  const int b = bh >> 2;
  const int h = bh & 3;
  const int tid = threadIdx.x;
  const int wid = tid >> 6;
  const int lane = tid & 63;
  const int g = lane >> 4;
  const int ql = lane & 15;
  const int qw = blockIdx.x * 64 + wid * 16;
  const int jbase = blockIdx.z * (SEQ / NSPLIT);
  const int NT = (SEQ / NSPLIT) / KVB;

  const unsigned short* xb = xbf + ((size_t)b * SEQ) * FDIM + h * HD;

  // Q fragment, pre-scaled by log2(e) so exp(x) == exp2(score)
  bf16x8 qraw = __builtin_bit_cast(bf16x8,
      *reinterpret_cast<const uint4*>(xb + (size_t)(qw + ql) * FDIM + g * 8));
  bf16x8 qf;
#pragma unroll
  for (int e = 0; e < 8; ++e) qf[e] = (__bf16)((float)qraw[e] * LOG2E);

  bf16x8 ones;
#pragma unroll
  for (int e = 0; e < 8; ++e) ones[e] = (__bf16)1.0f;
  const f32x4 zf = {0.f, 0.f, 0.f, 0.f};

  f32x4 acc0 = {0.f, 0.f, 0.f, 0.f};  // O[row=4g+r][col=ql]
  f32x4 acc1 = {0.f, 0.f, 0.f, 0.f};  // O[row=4g+r][col=16+ql]
  f32x4 accL = {0.f, 0.f, 0.f, 0.f};  // l[row=4g+r]

  const unsigned long long* brow = bits + (size_t)(qw + ql) * (SEQ / 64);
  const int bcol0 = jbase >> 6;  // even for all NSPLIT in {1,2,4}

  // K staging map: thread -> rows (tid>>2, 64+(tid>>2)), 4-dword chunk tid&3
  const int krow = tid >> 2;
  const int kq = tid & 3;
  const unsigned short* kptr = xb + (size_t)(jbase + krow) * FDIM + kq * 8;

  // V staging map: rows (2pr, 2pr+1, 64+2pr, 64+2pr+1), cols 4*c4..4*c4+3;
  // pr bit-remapped so each wave's pi0h covers all 8 residues mod 8.
  const int s3 = (tid >> 3) & 7;
  const int pr = (s3 & 1) | (((s3 >> 1) & 1) << 1) | ((wid & 1) << 2) |
                 (((s3 >> 2) & 1) << 3) | ((wid >> 1) << 4);
  const int c4 = tid & 7;
  const unsigned short* sptr = xb + (size_t)(jbase + 2 * pr) * FDIM + c4 * 4;

  // pi(j) within a 64-half: j=[u|tp|g|r] -> [u|g|tp|r]; pi0h = pi(2pr)/2
  const int pi0h = 16 * (pr >> 4) + 4 * ((pr >> 1) & 3) + 2 * ((pr >> 3) & 1) + (pr & 1);

  const unsigned selA = 0x05040100u;  // [lo.b0, lo.b1, hi.b0, hi.b1]
  const unsigned selB = 0x07060302u;  // [lo.b2, lo.b3, hi.b2, hi.b3]

  // prologue: load + stage tile 0 into buffer 0
  uint4 k0 = *reinterpret_cast<const uint4*>(kptr);
  uint4 k1 = *reinterpret_cast<const uint4*>(kptr + 64 * FDIM);
  uint2 r0 = *reinterpret_cast<const uint2*>(sptr);
  uint2 r1 = *reinterpret_cast<const uint2*>(sptr + FDIM);
  uint2 r2 = *reinterpret_cast<const uint2*>(sptr + 64 * FDIM);
  uint2 r3 = *reinterpret_cast<const uint2*>(sptr + 65 * FDIM);
  uint4 wnv = *reinterpret_cast<const uint4*>(&brow[bcol0]);
  unsigned long long wc0 = (unsigned long long)wnv.x | ((unsigned long long)wnv.y << 32);
  unsigned long long wc1 = (unsigned long long)wnv.z | ((unsigned long long)wnv.w << 32);
  *reinterpret_cast<uint4*>(&Kl[0][krow][kq * 8]) = k0;
  *reinterpret_cast<uint4*>(&Kl[0][64 + krow][kq * 8]) = k1;
  {
    unsigned* vw = reinterpret_cast<unsigned*>(&Vp[0][0]) + pi0h;
    vw[(4 * c4 + 0) * 68] = __builtin_amdgcn_perm(r1.x, r0.x, selA);
    vw[(4 * c4 + 1) * 68] = __builtin_amdgcn_perm(r1.x, r0.x, selB);
    vw[(4 * c4 + 2) * 68] = __builtin_amdgcn_perm(r1.y, r0.y, selA);
    vw[(4 * c4 + 3) * 68] = __builtin_amdgcn_perm(r1.y, r0.y, selB);
    vw[(4 * c4 + 0) * 68 + 32] = __builtin_amdgcn_perm(r3.x, r2.x, selA);
    vw[(4 * c4 + 1) * 68 + 32] = __builtin_amdgcn_perm(r3.x, r2.x, selB);
    vw[(4 * c4 + 2) * 68 + 32] = __builtin_amdgcn_perm(r3.y, r2.y, selA);
    vw[(4 * c4 + 3) * 68 + 32] = __builtin_amdgcn_perm(r3.y, r2.y, selB);
  }

  for (int t = 0; t < NT; t += 2) {
    STEP(t, 0, 1);
    STEP(t + 1, 1, 0);
  }

  if (NSPLIT == 1) {
#pragma unroll
    for (int r = 0; r < 4; ++r) {
      const float inv = 1.f / accL[r];
      const size_t o = ((size_t)b * SEQ + (size_t)(qw + 4 * g + r)) * FDIM + h * HD;
      dst[o + ql] = acc0[r] * inv;
      dst[o + 16 + ql] = acc1[r] * inv;
    }
  } else {
    float* Op = dst + (((size_t)blockIdx.z * (NB * NH) + bh) * SEQ) * HD;
#pragma unroll
    for (int r = 0; r < 4; ++r) {
      const int q = qw + 4 * g + r;
      Op[(size_t)q * HD + ql] = acc0[r];
      Op[(size_t)q * HD + 16 + ql] = acc1[r];
    }
    if (ql == 0) {
#pragma unroll
      for (int r = 0; r < 4; ++r)
        lbuf[(size_t)blockIdx.z * NROWS + (size_t)bh * SEQ + qw + 4 * g + r] = accL[r];
    }
  }
}

// ---- combine partials (split path): out = sum(O_s) / sum(l_s) ----
template <int NSPLIT>
__global__ __launch_bounds__(256) void combine_kernel(
    const float* __restrict__ Op, const float* __restrict__ lbuf, float* __restrict__ out) {
  const int idx = blockIdx.x * 256 + threadIdx.x;  // unit: 4 floats
  const int row = idx >> 3;
  const int dc = (idx & 7) * 4;
  float lt = 0.f;
  float4 o = {0.f, 0.f, 0.f, 0.f};
#pragma unroll
  for (int s = 0; s < NSPLIT; ++s) {
    lt += lbuf[(size_t)s * NROWS + row];
    float4 v = *reinterpret_cast<const float4*>(Op + ((size_t)s * NROWS + row) * HD + dc);
    o.x += v.x; o.y += v.y; o.z += v.z; o.w += v.w;
  }
  const float inv = 1.f / lt;
  const int bh = row >> 12;
  const int q = row & (SEQ - 1);
  const int b = bh >> 2;
  const int h = bh & 3;
  float4 w;
  w.x = o.x * inv; w.y = o.y * inv; w.z = o.z * inv; w.w = o.w * inv;
  *reinterpret_cast<float4*>(out + ((size_t)b * SEQ + q) * FDIM + h * HD + dc) = w;
}

extern "C" void kernel_launch(void* const* d_in, const int* in_sizes, int n_in,
                              void* d_out, int out_size, void* d_ws, size_t ws_size,
                              hipStream_t stream) {
  (void)in_sizes; (void)n_in; (void)out_size;
  const float* x = (const float*)d_in[0];
  const int* adj = (const int*)d_in[1];
  float* outp = (float*)d_out;

  unsigned short* xbf = (unsigned short*)d_ws;                           // 2 MiB
  unsigned short* bits16 = (unsigned short*)((char*)d_ws + (2u << 20));  // 2 MiB
  float* Opart = (float*)((char*)d_ws + (4u << 20));
  auto need = [](int s) {
    return (size_t)(4u << 20) + (size_t)s * NROWS * HD * 4 + (size_t)s * NROWS * 4;
  };

  cvt_kernel<<<(NB * SEQ * FDIM) / (256 * 4), 256, 0, stream>>>(x, xbf);
  adjpack_kernel<<<(SEQ * SEQ) / (16 * 256), 256, 0, stream>>>(adj, bits16);

  const unsigned long long* bits = (const unsigned long long*)bits16;
  if (ws_size >= need(4)) {
    float* mlb = (float*)((char*)d_ws + (4u << 20) + (size_t)4 * NROWS * HD * 4);
    dim3 grid(SEQ / 64, NB * NH, 4);
    gat_kernel<4><<<grid, 256, 0, stream>>>(xbf, bits, Opart, mlb);
    combine_kernel<4><<<(NROWS * 8) / 256, 256, 0, stream>>>(Opart, mlb, outp);
  } else if (ws_size >= need(2)) {
    float* mlb = (float*)((char*)d_ws + (4u << 20) + (size_t)2 * NROWS * HD * 4);
    dim3 grid(SEQ / 64, NB * NH, 2);
    gat_kernel<2><<<grid, 256, 0, stream>>>(xbf, bits, Opart, mlb);
    combine_kernel<2><<<(NROWS * 8) / 256, 256, 0, stream>>>(Opart, mlb, outp);
  } else {
    dim3 grid(SEQ / 64, NB * NH, 1);
    gat_kernel<1><<<grid, 256, 0, stream>>>(xbf, bits, outp, nullptr);
  }
}